// Round 18
// baseline (1132.077 us; speedup 1.0000x reference)
//
#include <hip/hip_runtime.h>

typedef unsigned short u16;
typedef unsigned int u32;

__device__ __forceinline__ float bf2f(u16 u){ return __uint_as_float(((u32)u) << 16); }
__device__ __forceinline__ u16 f2bf(float f){
  u32 u = __float_as_uint(f);
  u32 r = u + 0x7fffu + ((u >> 16) & 1u);
  return (u16)(r >> 16);
}
__device__ __forceinline__ float lo2f(u32 u){ return __uint_as_float(u << 16); }
__device__ __forceinline__ float hi2f(u32 u){ return __uint_as_float(u & 0xffff0000u); }
__device__ __forceinline__ float sigf(float x){ return 1.0f / (1.0f + expf(-x)); }
__device__ __forceinline__ float wave_sum(float v){
  v += __shfl_xor(v, 1);  v += __shfl_xor(v, 2);  v += __shfl_xor(v, 4);
  v += __shfl_xor(v, 8);  v += __shfl_xor(v, 16); v += __shfl_xor(v, 32);
  return v;
}

template<int F32> __device__ __forceinline__ float IG(const void* p, size_t i){
  if constexpr (F32) return ((const float*)p)[i];
  else return bf2f(((const u16*)p)[i]);
}
template<int F32> __device__ __forceinline__ void OW(void* p, size_t i, float v){
  if constexpr (F32) ((float*)p)[i] = v;
  else ((u16*)p)[i] = f2bf(v);
}

// ---------------------------------------------------------------------------
// k_detect_d: input dtype from `speed`. flag: 0 = bf16, 1 = f32
// ---------------------------------------------------------------------------
__global__ void k_detect_d(const void* speed, int* flag)
{
  if (threadIdx.x == 0 && blockIdx.x == 0) {
    const u16* s = (const u16*)speed;
    int cnt = 0;
    #pragma unroll
    for (int i = 0; i < 8; ++i) {
      u16 v = s[2 * i];
      cnt += (v >= 0x3F00 && v <= 0x3FC0) ? 1 : 0;
    }
    flag[0] = (cnt >= 6) ? 0 : 1;
  }
}

// ---------------------------------------------------------------------------
// k_init_d: build pin[144][32], hspd[512][32], spkr_rn[64][32] (f32, [k][n])
// ---------------------------------------------------------------------------
template<int F32>
__global__ __launch_bounds__(256) void k_init_d(
    const int* __restrict__ flag,
    const void* __restrict__ dec, const void* __restrict__ spkr, const void* __restrict__ speed,
    const void* __restrict__ spd1_w, const void* __restrict__ spd1_b,
    float* __restrict__ pin, float* __restrict__ hspd, float* __restrict__ spkr_rn)
{
  if (flag[0] != F32) return;
  int idx = blockIdx.x * 256 + threadIdx.x;
  if (idx < 144 * 32) {
    int k = idx >> 5, n = idx & 31;
    float v = (k < 80) ? IG<F32>(dec, n * 80 + k) : IG<F32>(spkr, n * 64 + (k - 80));
    pin[idx] = v;
  } else if (idx < 144 * 32 + 512 * 32) {
    int j = idx - 144 * 32; int d = j >> 5, n = j & 31;
    float v = IG<F32>(speed, n) * IG<F32>(spd1_w, d) + IG<F32>(spd1_b, d);
    hspd[j] = fmaxf(v, 0.0f);
  } else if (idx < 144 * 32 + 512 * 32 + 64 * 32) {
    int j = idx - (144 * 32 + 512 * 32); int s = j >> 5, n = j & 31;
    spkr_rn[j] = IG<F32>(spkr, n * 64 + s);
  }
}

// ---------------------------------------------------------------------------
// piece fetch from up to 4 concatenated [k][32] f32 pieces
// ---------------------------------------------------------------------------
__device__ __forceinline__ float piece_fetch(int gk, int pn,
    const float* __restrict__ xa, int Ka, const float* __restrict__ xb, int Kb,
    const float* __restrict__ xc, int Kc, const float* __restrict__ xd)
{
  if (gk < Ka) return xa[(size_t)gk * 32 + pn];
  gk -= Ka;
  if (gk < Kb) return xb[(size_t)gk * 32 + pn];
  gk -= Kb;
  if (gk < Kc) return xc[(size_t)gk * 32 + pn];
  gk -= Kc;
  return xd[(size_t)gk * 32 + pn];
}

// ---------------------------------------------------------------------------
// k_gv_d: batched GEMV, out[r][n] = act(sum_k x[n,k]W[r,k] + b1[wr] + b2[wr])
// 8 rows x 32 batch per 256-thr block. Round-18: NO LDS STAGING — x is
// <=256 KB and L2-resident (guide: stage only what doesn't cache-fit).
// Per 8-pair iteration: 2 batched uint4 weight loads + 16 coalesced x loads,
// all independent; 4 accumulators; zero barriers; zero LDS.
// All pair-counts are multiples of 8 (K in {144,512,1024,1088,2048,3136}).
// rowmap=1 (LSTM): wr = r + (r>=2048 ? 2048 : 0)
// ---------------------------------------------------------------------------
template<int F32>
__global__ __launch_bounds__(256) void k_gv_d(
    const int* __restrict__ flag,
    const float* __restrict__ xa, int Ka,
    const float* __restrict__ xb, int Kb,
    const float* __restrict__ xc, int Kc,
    const float* __restrict__ xd,
    const void* __restrict__ W,
    const void* __restrict__ bias1,
    const void* __restrict__ bias2,
    float* __restrict__ out,
    int K, int rowmap, int act)
{
  if (flag[0] != F32) return;
  int tid = threadIdx.x;
  int n = tid & 31;
  int rl = tid >> 5;
  int r = blockIdx.x * 8 + rl;
  int wr = r;
  if (rowmap && r >= 2048) wr = r + 2048;
  float acc0 = 0.0f, acc1 = 0.0f, acc2 = 0.0f, acc3 = 0.0f;

  if constexpr (F32) {
    const float4* wq = reinterpret_cast<const float4*>((const float*)W + (size_t)wr * (size_t)K);
    for (int k0 = 0; k0 < K; k0 += 8) {
      float4 w0 = wq[(k0 >> 2)];
      float4 w1 = wq[(k0 >> 2) + 1];
      float xv[8];
      #pragma unroll
      for (int j = 0; j < 8; ++j)
        xv[j] = piece_fetch(k0 + j, n, xa, Ka, xb, Kb, xc, Kc, xd);
      acc0 = fmaf(xv[0], w0.x, acc0); acc0 = fmaf(xv[1], w0.y, acc0);
      acc1 = fmaf(xv[2], w0.z, acc1); acc1 = fmaf(xv[3], w0.w, acc1);
      acc2 = fmaf(xv[4], w1.x, acc2); acc2 = fmaf(xv[5], w1.y, acc2);
      acc3 = fmaf(xv[6], w1.z, acc3); acc3 = fmaf(xv[7], w1.w, acc3);
    }
  } else {
    const uint4* wq = reinterpret_cast<const uint4*>((const u16*)W + (size_t)wr * (size_t)K);
    int npairs = K >> 1;                 // multiple of 8 for all K used
    for (int p0 = 0; p0 < npairs; p0 += 8) {
      uint4 wA = wq[(p0 >> 2)];
      uint4 wB = wq[(p0 >> 2) + 1];
      float xv[16];
      #pragma unroll
      for (int j = 0; j < 16; ++j)
        xv[j] = piece_fetch(2 * p0 + j, n, xa, Ka, xb, Kb, xc, Kc, xd);
      acc0 = fmaf(xv[ 0], lo2f(wA.x), acc0); acc0 = fmaf(xv[ 1], hi2f(wA.x), acc0);
      acc0 = fmaf(xv[ 2], lo2f(wA.y), acc0); acc0 = fmaf(xv[ 3], hi2f(wA.y), acc0);
      acc1 = fmaf(xv[ 4], lo2f(wA.z), acc1); acc1 = fmaf(xv[ 5], hi2f(wA.z), acc1);
      acc1 = fmaf(xv[ 6], lo2f(wA.w), acc1); acc1 = fmaf(xv[ 7], hi2f(wA.w), acc1);
      acc2 = fmaf(xv[ 8], lo2f(wB.x), acc2); acc2 = fmaf(xv[ 9], hi2f(wB.x), acc2);
      acc2 = fmaf(xv[10], lo2f(wB.y), acc2); acc2 = fmaf(xv[11], hi2f(wB.y), acc2);
      acc3 = fmaf(xv[12], lo2f(wB.z), acc3); acc3 = fmaf(xv[13], hi2f(wB.z), acc3);
      acc3 = fmaf(xv[14], lo2f(wB.w), acc3); acc3 = fmaf(xv[15], hi2f(wB.w), acc3);
    }
  }
  float acc = (acc0 + acc1) + (acc2 + acc3);
  if (bias1) acc += IG<F32>(bias1, wr);
  if (bias2) acc += IG<F32>(bias2, wr);
  if (act == 1) acc = fmaxf(acc, 0.0f);
  else if (act == 2) acc = tanhf(acc);
  out[(size_t)r * 32 + n] = acc;
}

// ---------------------------------------------------------------------------
// k_attlog_d: one block per (t, n); 256 threads = 256 attention dims
// ---------------------------------------------------------------------------
template<int F32>
__global__ __launch_bounds__(256) void k_attlog_d(
    const int* __restrict__ flag,
    const void* __restrict__ enc, const void* __restrict__ spkr, const void* __restrict__ speed,
    const void* __restrict__ enc_w, const void* __restrict__ enc_b, const void* __restrict__ spkr_w,
    const void* __restrict__ conv_w, const void* __restrict__ speed_att_w,
    const void* __restrict__ attproj_w, const void* __restrict__ attproj_b,
    float* __restrict__ logits)
{
  if (flag[0] != F32) return;
  int t = blockIdx.x;   // 0..9
  int n = blockIdx.y;   // 0..31
  int tid = threadIdx.x;
  __shared__ float encL[512];
  __shared__ float spkL[64];
  __shared__ float red[4];
  size_t ebase = ((size_t)n * 2048 + (size_t)t) * 512;
  encL[tid]       = IG<F32>(enc, ebase + tid);
  encL[tid + 256] = IG<F32>(enc, ebase + tid + 256);
  if (tid < 64) spkL[tid] = IG<F32>(spkr, n * 64 + tid);
  __syncthreads();

  int a = tid;
  float ss = 0.0f, d = 0.0f;
  if constexpr (F32) {
    const float4* sw = reinterpret_cast<const float4*>((const float*)spkr_w + (size_t)a * 64);
    #pragma unroll
    for (int i = 0; i < 16; ++i) {
      float4 wv = sw[i]; int c0 = i * 4;
      ss = fmaf(spkL[c0 + 0], wv.x, ss); ss = fmaf(spkL[c0 + 1], wv.y, ss);
      ss = fmaf(spkL[c0 + 2], wv.z, ss); ss = fmaf(spkL[c0 + 3], wv.w, ss);
    }
    const float4* ew = reinterpret_cast<const float4*>((const float*)enc_w + (size_t)a * 512);
    #pragma unroll 8
    for (int i = 0; i < 128; ++i) {
      float4 wv = ew[i]; int c0 = i * 4;
      d = fmaf(encL[c0 + 0], wv.x, d); d = fmaf(encL[c0 + 1], wv.y, d);
      d = fmaf(encL[c0 + 2], wv.z, d); d = fmaf(encL[c0 + 3], wv.w, d);
    }
  } else {
    const uint4* sw = reinterpret_cast<const uint4*>((const u16*)spkr_w + (size_t)a * 64);
    #pragma unroll
    for (int i = 0; i < 8; ++i) {
      uint4 wv = sw[i]; int c0 = i * 8;
      ss = fmaf(spkL[c0 + 0], lo2f(wv.x), ss); ss = fmaf(spkL[c0 + 1], hi2f(wv.x), ss);
      ss = fmaf(spkL[c0 + 2], lo2f(wv.y), ss); ss = fmaf(spkL[c0 + 3], hi2f(wv.y), ss);
      ss = fmaf(spkL[c0 + 4], lo2f(wv.z), ss); ss = fmaf(spkL[c0 + 5], hi2f(wv.z), ss);
      ss = fmaf(spkL[c0 + 6], lo2f(wv.w), ss); ss = fmaf(spkL[c0 + 7], hi2f(wv.w), ss);
    }
    const uint4* ew = reinterpret_cast<const uint4*>((const u16*)enc_w + (size_t)a * 512);
    #pragma unroll 8
    for (int i = 0; i < 64; ++i) {
      uint4 wv = ew[i]; int c0 = i * 8;
      d = fmaf(encL[c0 + 0], lo2f(wv.x), d); d = fmaf(encL[c0 + 1], hi2f(wv.x), d);
      d = fmaf(encL[c0 + 2], lo2f(wv.y), d); d = fmaf(encL[c0 + 3], hi2f(wv.y), d);
      d = fmaf(encL[c0 + 4], lo2f(wv.z), d); d = fmaf(encL[c0 + 5], hi2f(wv.z), d);
      d = fmaf(encL[c0 + 6], lo2f(wv.w), d); d = fmaf(encL[c0 + 7], hi2f(wv.w), d);
    }
  }
  float bspk = ss / (1.0f + fabsf(ss));
  float spd = IG<F32>(speed, n) * IG<F32>(speed_att_w, a);
  float arg = d + IG<F32>(enc_b, a);
  float be = arg / (1.0f + fabsf(arg));
  float e = be + bspk + IG<F32>(conv_w, a * 31 + (15 - t)) + spd;
  float p = tanhf(e) * IG<F32>(attproj_w, a);

  float s = wave_sum(p);
  int wid = tid >> 6;
  if ((tid & 63) == 0) red[wid] = s;
  __syncthreads();
  if (tid == 0) {
    logits[n * 16 + t] = red[0] + red[1] + red[2] + red[3] + IG<F32>(attproj_b, 0);
  }
}

// ---------------------------------------------------------------------------
// k_ctx_d: per-n masked softmax over window + context
// ---------------------------------------------------------------------------
template<int F32>
__global__ __launch_bounds__(256) void k_ctx_d(
    const int* __restrict__ flag,
    const void* __restrict__ enc, const int* __restrict__ lengths,
    const float* __restrict__ logits, const float* __restrict__ sp,
    float* __restrict__ ctx, void* __restrict__ out)
{
  if (flag[0] != F32) return;
  int n = blockIdx.x, tid = threadIdx.x;
  __shared__ float wL[10];
  if (tid == 0) {
    int lm1 = lengths[n] - 1;
    float lf[10]; float m = -3.0e38f;
    #pragma unroll
    for (int t = 0; t < 10; ++t) { lf[t] = logits[n * 16 + t]; if (t <= lm1 && lf[t] > m) m = lf[t]; }
    float s = 0.0f, w[10];
    #pragma unroll
    for (int t = 0; t < 10; ++t) { w[t] = (t <= lm1) ? expf(lf[t] - m) : 0.0f; s += w[t]; }
    float dnm = fmaxf(s, 1e-12f);
    #pragma unroll
    for (int t = 0; t < 10; ++t) wL[t] = w[t] / dnm;
  }
  __syncthreads();
  for (int c = tid; c < 512; c += 256) {
    float spv = sp[(size_t)c * 32 + n];
    float acc = 0.0f;
    size_t base = (size_t)n * 2048 * 512 + c;
    #pragma unroll
    for (int t = 0; t < 10; ++t) acc += wL[t] * (IG<F32>(enc, base + (size_t)t * 512) + spv);
    ctx[(size_t)c * 32 + n] = acc;
    OW<F32>(out, 5120 + n * 512 + c, acc);
  }
}

// ---------------------------------------------------------------------------
// k_act_d: LSTM gate activation
// ---------------------------------------------------------------------------
__global__ __launch_bounds__(256) void k_act_d(const float* __restrict__ g, float* __restrict__ h)
{
  int f = blockIdx.x * 256 + threadIdx.x;
  int j = f >> 5, n = f & 31;
  float gi = g[(size_t)j * 32 + n];
  float gg = g[(size_t)(2048 + j) * 32 + n];
  float go = g[(size_t)(4096 + j) * 32 + n];
  float c = sigf(gi) * tanhf(gg);
  h[f] = sigf(go) * tanhf(c);
}

// ---------------------------------------------------------------------------
// k_ln_d: x = LayerNorm(x + delta) * g + b   (per n; 512 threads)
// ---------------------------------------------------------------------------
template<int F32>
__global__ __launch_bounds__(512) void k_ln_d(
    const int* __restrict__ flag,
    float* __restrict__ x, const float* __restrict__ delta,
    const void* __restrict__ lg, const void* __restrict__ lb)
{
  if (flag[0] != F32) return;
  int n = blockIdx.x, tid = threadIdx.x;
  __shared__ float red[18];
  float y = x[(size_t)tid * 32 + n] + delta[(size_t)tid * 32 + n];
  float s1 = wave_sum(y), s2 = wave_sum(y * y);
  int wid = tid >> 6;
  if ((tid & 63) == 0) { red[wid] = s1; red[8 + wid] = s2; }
  __syncthreads();
  if (tid == 0) {
    float t1 = 0, t2 = 0;
    for (int i = 0; i < 8; ++i) { t1 += red[i]; t2 += red[8 + i]; }
    float mu = t1 * (1.0f / 512.0f);
    float var = t2 * (1.0f / 512.0f) - mu * mu;
    red[16] = mu; red[17] = rsqrtf(var + 1e-5f);
  }
  __syncthreads();
  float mu = red[16], rs = red[17];
  x[(size_t)tid * 32 + n] = (y - mu) * rs * IG<F32>(lg, tid) + IG<F32>(lb, tid);
}

// ---------------------------------------------------------------------------
// k_out_d: final projection to (N,160)
// ---------------------------------------------------------------------------
template<int F32>
__global__ __launch_bounds__(256) void k_out_d(
    const int* __restrict__ flag,
    const float* __restrict__ x, const void* __restrict__ W, const void* __restrict__ bias,
    void* __restrict__ out)
{
  if (flag[0] != F32) return;
  int n = blockIdx.x, tid = threadIdx.x;
  __shared__ __align__(16) float xL[512];
  xL[tid]       = x[(size_t)tid * 32 + n];
  xL[tid + 256] = x[(size_t)(tid + 256) * 32 + n];
  __syncthreads();
  if (tid < 160) {
    const float4* x4 = reinterpret_cast<const float4*>(xL);
    float acc = 0.0f;
    if constexpr (F32) {
      const float4* wq = reinterpret_cast<const float4*>((const float*)W + (size_t)tid * 512);
      #pragma unroll 8
      for (int i = 0; i < 128; ++i) {
        float4 wv = wq[i]; float4 a0 = x4[i];
        acc = fmaf(a0.x, wv.x, acc); acc = fmaf(a0.y, wv.y, acc);
        acc = fmaf(a0.z, wv.z, acc); acc = fmaf(a0.w, wv.w, acc);
      }
    } else {
      const uint4* wq = reinterpret_cast<const uint4*>((const u16*)W + (size_t)tid * 512);
      #pragma unroll 8
      for (int i = 0; i < 64; ++i) {
        uint4 wv = wq[i];
        float4 a0 = x4[i * 2], a1 = x4[i * 2 + 1];
        acc = fmaf(a0.x, lo2f(wv.x), acc); acc = fmaf(a0.y, hi2f(wv.x), acc);
        acc = fmaf(a0.z, lo2f(wv.y), acc); acc = fmaf(a0.w, hi2f(wv.y), acc);
        acc = fmaf(a1.x, lo2f(wv.z), acc); acc = fmaf(a1.y, hi2f(wv.z), acc);
        acc = fmaf(a1.z, lo2f(wv.w), acc); acc = fmaf(a1.w, hi2f(wv.w), acc);
      }
    }
    OW<F32>(out, n * 160 + tid, acc + IG<F32>(bias, tid));
  }
}

// ---------------------------------------------------------------------------
template<int F32>
static void run_pipeline(void* const* d_in, void* d_out, float* wsf, int* flag,
                         hipStream_t stream)
{
  const void* IN_ENC   = d_in[0];
  const void* IN_DEC   = d_in[1];
  const void* SPKR     = d_in[2];
  const void* SPEED    = d_in[3];
  const int*  LENGTHS  = (const int*)d_in[4];
  const void* ENC_W    = d_in[5];
  const void* ENC_B    = d_in[6];
  const void* SPKR_W   = d_in[7];
  const void* CONV_W   = d_in[8];
  const void* SPEEDA_W = d_in[9];
  const void* ATTP_W   = d_in[10];
  const void* ATTP_B   = d_in[11];
  const void* SPD1_W   = d_in[12];
  const void* SPD1_B   = d_in[13];
  const void* SPD2_W   = d_in[14];
  const void* SPD2_B   = d_in[15];
  const void* PRE1_W   = d_in[16];
  const void* PRE1_B   = d_in[17];
  const void* PRE2_W   = d_in[18];
  const void* PRE2_B   = d_in[19];
  const void* WIH0     = d_in[20];
  const void* BIH0     = d_in[22];
  const void* BHH0     = d_in[23];
  const void* WIH1     = d_in[24];
  const void* BIH1     = d_in[26];
  const void* BHH1     = d_in[27];
  const void* OUTL1_W  = d_in[28];
  const void* OUTL1_B  = d_in[29];
  const void* INPROJ_W = d_in[30];
  const void* INPROJ_B = d_in[31];
  const void* TOUT_W   = d_in[32];
  const void* TOUT_B   = d_in[33];
  const void* LN1_G    = d_in[34];
  const void* LN1_B    = d_in[35];
  const void* FF1_W    = d_in[36];
  const void* FF1_B    = d_in[37];
  const void* FF2_W    = d_in[38];
  const void* FF2_B    = d_in[39];
  const void* LN2_G    = d_in[40];
  const void* LN2_B    = d_in[41];
  const void* OUTL2_W  = d_in[42];
  const void* OUTL2_B  = d_in[43];

  float* pin     = wsf + 0;        // [144][32]
  float* hspd    = wsf + 4608;     // [512][32]
  float* spkr_rn = wsf + 20992;    // [64][32]
  float* sp      = wsf + 23040;    // [512][32]
  float* logits  = wsf + 39424;    // [32][16]
  float* ctx     = wsf + 39936;    // [512][32]
  float* prehid  = wsf + 56320;    // [1024][32]
  float* pre     = wsf + 89088;    // [512][32]
  float* g0      = wsf + 105472;   // [6144][32]
  float* h1      = wsf + 302080;   // [2048][32]
  float* g1      = g0;             // g0 dead after h1
  float* h2      = wsf + 367616;   // [2048][32]
  float* xs      = wsf + 433152;   // [512][32]
  float* vbuf    = wsf + 105472;   // transformer scratch in dead g0/g1 region
  float* abuf    = wsf + 121856;
  float* hbuf    = wsf + 138240;
  float* fbuf    = wsf + 171008;

  k_init_d<F32><<<90, 256, 0, stream>>>(flag, IN_DEC, SPKR, SPEED, SPD1_W, SPD1_B,
                                        pin, hspd, spkr_rn);
  // sp = tanh(spd2_w @ hspd + b)   M=512 K=512
  k_gv_d<F32><<<64, 256, 0, stream>>>(flag, hspd, 512, hspd, 0, hspd, 0, hspd,
                                      SPD2_W, SPD2_B, nullptr, sp, 512, 0, 2);
  k_attlog_d<F32><<<dim3(10, 32), 256, 0, stream>>>(flag, IN_ENC, SPKR, SPEED,
                                      ENC_W, ENC_B, SPKR_W, CONV_W, SPEEDA_W,
                                      ATTP_W, ATTP_B, logits);
  k_ctx_d<F32><<<32, 256, 0, stream>>>(flag, IN_ENC, LENGTHS, logits, sp, ctx, d_out);
  // prehid = relu(pre1_w @ pin + b)   M=1024 K=144
  k_gv_d<F32><<<128, 256, 0, stream>>>(flag, pin, 144, pin, 0, pin, 0, pin,
                                       PRE1_W, PRE1_B, nullptr, prehid, 144, 0, 1);
  // pre = relu(pre2_w @ prehid + b)   M=512 K=1024
  k_gv_d<F32><<<64, 256, 0, stream>>>(flag, prehid, 1024, prehid, 0, prehid, 0, prehid,
                                      PRE2_W, PRE2_B, nullptr, pre, 1024, 0, 1);
  // g0: rows 6144 (i,gg,o), K=1088 = [pre, ctx, spkr]
  k_gv_d<F32><<<768, 256, 0, stream>>>(flag, pre, 512, ctx, 512, spkr_rn, 64, pre,
                                       WIH0, BIH0, BHH0, g0, 1088, 1, 0);
  k_act_d<<<256, 256, 0, stream>>>(g0, h1);
  // g1: rows 6144, K=2048
  k_gv_d<F32><<<768, 256, 0, stream>>>(flag, h1, 2048, h1, 0, h1, 0, h1,
                                       WIH1, BIH1, BHH1, g1, 2048, 1, 0);
  k_act_d<<<256, 256, 0, stream>>>(g1, h2);
  // xs = outl1_w @ [h2,pre,ctx,spkr] + b   M=512 K=3136
  k_gv_d<F32><<<64, 256, 0, stream>>>(flag, h2, 2048, pre, 512, ctx, 512, spkr_rn,
                                      OUTL1_W, OUTL1_B, nullptr, xs, 3136, 0, 0);

  for (int l = 0; l < 2; ++l) {
    const char* Wv = (const char*)INPROJ_W; const char* bv = (const char*)INPROJ_B;
    const char* Wo = (const char*)TOUT_W;   const char* bo = (const char*)TOUT_B;
    const char* W1 = (const char*)FF1_W;    const char* W2 = (const char*)FF2_W;
    int esz = F32 ? 4 : 2;
    // v = Wv @ xs + bv      M=512 K=512
    k_gv_d<F32><<<64, 256, 0, stream>>>(flag, xs, 512, xs, 0, xs, 0, xs,
        Wv + ((size_t)l * 786432 + 524288) * esz,
        bv + ((size_t)l * 1536 + 1024) * esz, nullptr, vbuf, 512, 0, 0);
    // a = Wo @ v + bo       M=512 K=512
    k_gv_d<F32><<<64, 256, 0, stream>>>(flag, vbuf, 512, vbuf, 0, vbuf, 0, vbuf,
        Wo + ((size_t)l * 262144) * esz,
        bo + ((size_t)l * 512) * esz, nullptr, abuf, 512, 0, 0);
    k_ln_d<F32><<<32, 512, 0, stream>>>(flag, xs, abuf,
        (const char*)LN1_G + (size_t)l * 512 * esz,
        (const char*)LN1_B + (size_t)l * 512 * esz);
    // h = relu(W1 @ xs + b1)  M=1024 K=512
    k_gv_d<F32><<<128, 256, 0, stream>>>(flag, xs, 512, xs, 0, xs, 0, xs,
        W1 + ((size_t)l * 524288) * esz,
        (const char*)FF1_B + (size_t)l * 1024 * esz, nullptr, hbuf, 512, 0, 1);
    // f = W2 @ h + b2       M=512 K=1024
    k_gv_d<F32><<<64, 256, 0, stream>>>(flag, hbuf, 1024, hbuf, 0, hbuf, 0, hbuf,
        W2 + ((size_t)l * 524288) * esz,
        (const char*)FF2_B + (size_t)l * 512 * esz, nullptr, fbuf, 1024, 0, 0);
    k_ln_d<F32><<<32, 512, 0, stream>>>(flag, xs, fbuf,
        (const char*)LN2_G + (size_t)l * 512 * esz,
        (const char*)LN2_B + (size_t)l * 512 * esz);
  }

  k_out_d<F32><<<32, 256, 0, stream>>>(flag, xs, OUTL2_W, OUTL2_B, d_out);
}

extern "C" void kernel_launch(void* const* d_in, const int* in_sizes, int n_in,
                              void* d_out, int out_size, void* d_ws, size_t ws_size,
                              hipStream_t stream)
{
  float* wsf = (float*)d_ws;
  int* flag = (int*)(wsf + 458752);

  k_detect_d<<<1, 64, 0, stream>>>(d_in[3], flag);

  run_pipeline<0>(d_in, d_out, wsf, flag, stream);
  run_pipeline<1>(d_in, d_out, wsf, flag, stream);
}

// Round 19
// 722.085 us; speedup vs baseline: 1.5678x; 1.5678x over previous
//
#include <hip/hip_runtime.h>

typedef unsigned short u16;
typedef unsigned int u32;

__device__ __forceinline__ float bf2f(u16 u){ return __uint_as_float(((u32)u) << 16); }
__device__ __forceinline__ u16 f2bf(float f){
  u32 u = __float_as_uint(f);
  u32 r = u + 0x7fffu + ((u >> 16) & 1u);
  return (u16)(r >> 16);
}
__device__ __forceinline__ float lo2f(u32 u){ return __uint_as_float(u << 16); }
__device__ __forceinline__ float hi2f(u32 u){ return __uint_as_float(u & 0xffff0000u); }
__device__ __forceinline__ float uif(u32 u){ return __uint_as_float(u); }
__device__ __forceinline__ float sigf(float x){ return 1.0f / (1.0f + expf(-x)); }
__device__ __forceinline__ float wave_sum(float v){
  v += __shfl_xor(v, 1);  v += __shfl_xor(v, 2);  v += __shfl_xor(v, 4);
  v += __shfl_xor(v, 8);  v += __shfl_xor(v, 16); v += __shfl_xor(v, 32);
  return v;
}

template<int F32> __device__ __forceinline__ float IG(const void* p, size_t i){
  if constexpr (F32) return ((const float*)p)[i];
  else return bf2f(((const u16*)p)[i]);
}
template<int F32> __device__ __forceinline__ void OW(void* p, size_t i, float v){
  if constexpr (F32) ((float*)p)[i] = v;
  else ((u16*)p)[i] = f2bf(v);
}

// ---------------------------------------------------------------------------
// k_detect_e: input dtype from `speed`. flag: 0 = bf16, 1 = f32
// ---------------------------------------------------------------------------
__global__ void k_detect_e(const void* speed, int* flag)
{
  if (threadIdx.x == 0 && blockIdx.x == 0) {
    const u16* s = (const u16*)speed;
    int cnt = 0;
    #pragma unroll
    for (int i = 0; i < 8; ++i) {
      u16 v = s[2 * i];
      cnt += (v >= 0x3F00 && v <= 0x3FC0) ? 1 : 0;
    }
    flag[0] = (cnt >= 6) ? 0 : 1;
  }
}

// ---------------------------------------------------------------------------
// k_init_e: build pin[144][32], hspd[512][32], spkr_rn[64][32] (f32, [k][n])
// ---------------------------------------------------------------------------
template<int F32>
__global__ __launch_bounds__(256) void k_init_e(
    const int* __restrict__ flag,
    const void* __restrict__ dec, const void* __restrict__ spkr, const void* __restrict__ speed,
    const void* __restrict__ spd1_w, const void* __restrict__ spd1_b,
    float* __restrict__ pin, float* __restrict__ hspd, float* __restrict__ spkr_rn)
{
  if (flag[0] != F32) return;
  int idx = blockIdx.x * 256 + threadIdx.x;
  if (idx < 144 * 32) {
    int k = idx >> 5, n = idx & 31;
    float v = (k < 80) ? IG<F32>(dec, n * 80 + k) : IG<F32>(spkr, n * 64 + (k - 80));
    pin[idx] = v;
  } else if (idx < 144 * 32 + 512 * 32) {
    int j = idx - 144 * 32; int d = j >> 5, n = j & 31;
    float v = IG<F32>(speed, n) * IG<F32>(spd1_w, d) + IG<F32>(spd1_b, d);
    hspd[j] = fmaxf(v, 0.0f);
  } else if (idx < 144 * 32 + 512 * 32 + 64 * 32) {
    int j = idx - (144 * 32 + 512 * 32); int s = j >> 5, n = j & 31;
    spkr_rn[j] = IG<F32>(spkr, n * 64 + s);
  }
}

// ---------------------------------------------------------------------------
// piece fetch from up to 4 concatenated [k][32] f32 pieces
// ---------------------------------------------------------------------------
__device__ __forceinline__ float piece_fetch(int gk, int pn,
    const float* __restrict__ xa, int Ka, const float* __restrict__ xb, int Kb,
    const float* __restrict__ xc, int Kc, const float* __restrict__ xd)
{
  if (gk < Ka) return xa[(size_t)gk * 32 + pn];
  gk -= Ka;
  if (gk < Kb) return xb[(size_t)gk * 32 + pn];
  gk -= Kb;
  if (gk < Kc) return xc[(size_t)gk * 32 + pn];
  gk -= Kc;
  return xd[(size_t)gk * 32 + pn];
}

// ---------------------------------------------------------------------------
// k_gv_e: batched GEMV, out[r][n] = act(sum_k x[n,k]W[r,k] + b1[wr] + b2[wr])
// 256-thr block; RPB rows per block (power of 2, <=8). Warp rl handles row
// blockIdx*RPB + (rl & (RPB-1)); warps with rl>=RPB duplicate rows (identical
// values, benign). RPB=8 == round-17 mapping exactly. RPB=2 quadruples the
// grid for small-M gemvs -> 4x outstanding cold-HBM weight fetches (round-19:
// top dispatch was fetch-latency-bound at 32 GB/s with only 64 blocks).
// Staged-broadcast bf16 body (round-13/17 proven, best measured).
// rowmap=1 (LSTM): wr = r + (r>=2048 ? 2048 : 0)
// ---------------------------------------------------------------------------
template<int F32>
__global__ __launch_bounds__(256) void k_gv_e(
    const int* __restrict__ flag,
    const float* __restrict__ xa, int Ka,
    const float* __restrict__ xb, int Kb,
    const float* __restrict__ xc, int Kc,
    const float* __restrict__ xd,
    const void* __restrict__ W,
    const void* __restrict__ bias1,
    const void* __restrict__ bias2,
    float* __restrict__ out,
    int K, int rowmap, int act, int rpb)
{
  if (flag[0] != F32) return;
  __shared__ u32 xbuf[128][33];          // 16.9 KB
  const int KCHE = F32 ? 128 : 256;      // k-elements staged per chunk
  int tid = threadIdx.x;
  int n = tid & 31;
  int rl = tid >> 5;
  int r = blockIdx.x * rpb + (rl & (rpb - 1));
  int wr = r;
  if (rowmap && r >= 2048) wr = r + 2048;
  float acc = 0.0f, acc1 = 0.0f, acc2 = 0.0f, acc3 = 0.0f;

  for (int k0 = 0; k0 < K; k0 += KCHE) {
    int kc = K - k0; if (kc > KCHE) kc = KCHE;
    if constexpr (F32) {
      for (int p = tid; p < kc * 32; p += 256) {
        int pn = p & 31, kk = p >> 5;
        xbuf[kk][pn] = __float_as_uint(piece_fetch(k0 + kk, pn, xa, Ka, xb, Kb, xc, Kc, xd));
      }
    } else {
      int pairs = kc >> 1;
      for (int p = tid; p < pairs * 32; p += 256) {
        int pn = p & 31, kk2 = p >> 5;
        int gk = k0 + 2 * kk2;
        float v0 = piece_fetch(gk,     pn, xa, Ka, xb, Kb, xc, Kc, xd);
        float v1 = piece_fetch(gk + 1, pn, xa, Ka, xb, Kb, xc, Kc, xd);
        xbuf[kk2][pn] = ((u32)f2bf(v1) << 16) | (u32)f2bf(v0);
      }
    }
    __syncthreads();
    if constexpr (F32) {
      const float4* wq = reinterpret_cast<const float4*>((const float*)W + (size_t)wr * (size_t)K + k0);
      for (int kk = 0; kk < kc; kk += 8) {
        float4 w0 = wq[(kk >> 2)];
        float4 w1 = wq[(kk >> 2) + 1];
        acc = fmaf(uif(xbuf[kk + 0][n]), w0.x, acc);
        acc = fmaf(uif(xbuf[kk + 1][n]), w0.y, acc);
        acc = fmaf(uif(xbuf[kk + 2][n]), w0.z, acc);
        acc = fmaf(uif(xbuf[kk + 3][n]), w0.w, acc);
        acc = fmaf(uif(xbuf[kk + 4][n]), w1.x, acc);
        acc = fmaf(uif(xbuf[kk + 5][n]), w1.y, acc);
        acc = fmaf(uif(xbuf[kk + 6][n]), w1.z, acc);
        acc = fmaf(uif(xbuf[kk + 7][n]), w1.w, acc);
      }
    } else {
      int pairs = kc >> 1;
      const uint4* wq = reinterpret_cast<const uint4*>((const u16*)W + (size_t)wr * (size_t)K + k0);
      int kk2 = 0;
      for (; kk2 + 16 <= pairs; kk2 += 16) {
        int q = kk2 >> 2;
        uint4 w0 = wq[q], w1 = wq[q + 1], w2 = wq[q + 2], w3 = wq[q + 3];
        u32 xw;
        xw = xbuf[kk2 +  0][n]; acc  = fmaf(lo2f(xw), lo2f(w0.x), acc ); acc  = fmaf(hi2f(xw), hi2f(w0.x), acc );
        xw = xbuf[kk2 +  1][n]; acc  = fmaf(lo2f(xw), lo2f(w0.y), acc ); acc  = fmaf(hi2f(xw), hi2f(w0.y), acc );
        xw = xbuf[kk2 +  2][n]; acc  = fmaf(lo2f(xw), lo2f(w0.z), acc ); acc  = fmaf(hi2f(xw), hi2f(w0.z), acc );
        xw = xbuf[kk2 +  3][n]; acc  = fmaf(lo2f(xw), lo2f(w0.w), acc ); acc  = fmaf(hi2f(xw), hi2f(w0.w), acc );
        xw = xbuf[kk2 +  4][n]; acc1 = fmaf(lo2f(xw), lo2f(w1.x), acc1); acc1 = fmaf(hi2f(xw), hi2f(w1.x), acc1);
        xw = xbuf[kk2 +  5][n]; acc1 = fmaf(lo2f(xw), lo2f(w1.y), acc1); acc1 = fmaf(hi2f(xw), hi2f(w1.y), acc1);
        xw = xbuf[kk2 +  6][n]; acc1 = fmaf(lo2f(xw), lo2f(w1.z), acc1); acc1 = fmaf(hi2f(xw), hi2f(w1.z), acc1);
        xw = xbuf[kk2 +  7][n]; acc1 = fmaf(lo2f(xw), lo2f(w1.w), acc1); acc1 = fmaf(hi2f(xw), hi2f(w1.w), acc1);
        xw = xbuf[kk2 +  8][n]; acc2 = fmaf(lo2f(xw), lo2f(w2.x), acc2); acc2 = fmaf(hi2f(xw), hi2f(w2.x), acc2);
        xw = xbuf[kk2 +  9][n]; acc2 = fmaf(lo2f(xw), lo2f(w2.y), acc2); acc2 = fmaf(hi2f(xw), hi2f(w2.y), acc2);
        xw = xbuf[kk2 + 10][n]; acc2 = fmaf(lo2f(xw), lo2f(w2.z), acc2); acc2 = fmaf(hi2f(xw), hi2f(w2.z), acc2);
        xw = xbuf[kk2 + 11][n]; acc2 = fmaf(lo2f(xw), lo2f(w2.w), acc2); acc2 = fmaf(hi2f(xw), hi2f(w2.w), acc2);
        xw = xbuf[kk2 + 12][n]; acc3 = fmaf(lo2f(xw), lo2f(w3.x), acc3); acc3 = fmaf(hi2f(xw), hi2f(w3.x), acc3);
        xw = xbuf[kk2 + 13][n]; acc3 = fmaf(lo2f(xw), lo2f(w3.y), acc3); acc3 = fmaf(hi2f(xw), hi2f(w3.y), acc3);
        xw = xbuf[kk2 + 14][n]; acc3 = fmaf(lo2f(xw), lo2f(w3.z), acc3); acc3 = fmaf(hi2f(xw), hi2f(w3.z), acc3);
        xw = xbuf[kk2 + 15][n]; acc3 = fmaf(lo2f(xw), lo2f(w3.w), acc3); acc3 = fmaf(hi2f(xw), hi2f(w3.w), acc3);
      }
      for (; kk2 < pairs; kk2 += 4) {
        uint4 wv = wq[kk2 >> 2];
        u32 xw;
        xw = xbuf[kk2 + 0][n]; acc = fmaf(lo2f(xw), lo2f(wv.x), acc); acc = fmaf(hi2f(xw), hi2f(wv.x), acc);
        xw = xbuf[kk2 + 1][n]; acc = fmaf(lo2f(xw), lo2f(wv.y), acc); acc = fmaf(hi2f(xw), hi2f(wv.y), acc);
        xw = xbuf[kk2 + 2][n]; acc = fmaf(lo2f(xw), lo2f(wv.z), acc); acc = fmaf(hi2f(xw), hi2f(wv.z), acc);
        xw = xbuf[kk2 + 3][n]; acc = fmaf(lo2f(xw), lo2f(wv.w), acc); acc = fmaf(hi2f(xw), hi2f(wv.w), acc);
      }
    }
    __syncthreads();
  }
  acc = (acc + acc1) + (acc2 + acc3);
  if (bias1) acc += IG<F32>(bias1, wr);
  if (bias2) acc += IG<F32>(bias2, wr);
  if (act == 1) acc = fmaxf(acc, 0.0f);
  else if (act == 2) acc = tanhf(acc);
  out[(size_t)r * 32 + n] = acc;
}

// ---------------------------------------------------------------------------
// k_attlog_e: one block per (t, n); 256 threads = 256 attention dims
// ---------------------------------------------------------------------------
template<int F32>
__global__ __launch_bounds__(256) void k_attlog_e(
    const int* __restrict__ flag,
    const void* __restrict__ enc, const void* __restrict__ spkr, const void* __restrict__ speed,
    const void* __restrict__ enc_w, const void* __restrict__ enc_b, const void* __restrict__ spkr_w,
    const void* __restrict__ conv_w, const void* __restrict__ speed_att_w,
    const void* __restrict__ attproj_w, const void* __restrict__ attproj_b,
    float* __restrict__ logits)
{
  if (flag[0] != F32) return;
  int t = blockIdx.x;   // 0..9
  int n = blockIdx.y;   // 0..31
  int tid = threadIdx.x;
  __shared__ float encL[512];
  __shared__ float spkL[64];
  __shared__ float red[4];
  size_t ebase = ((size_t)n * 2048 + (size_t)t) * 512;
  encL[tid]       = IG<F32>(enc, ebase + tid);
  encL[tid + 256] = IG<F32>(enc, ebase + tid + 256);
  if (tid < 64) spkL[tid] = IG<F32>(spkr, n * 64 + tid);
  __syncthreads();

  int a = tid;
  float ss = 0.0f, d = 0.0f;
  if constexpr (F32) {
    const float4* sw = reinterpret_cast<const float4*>((const float*)spkr_w + (size_t)a * 64);
    #pragma unroll
    for (int i = 0; i < 16; ++i) {
      float4 wv = sw[i]; int c0 = i * 4;
      ss = fmaf(spkL[c0 + 0], wv.x, ss); ss = fmaf(spkL[c0 + 1], wv.y, ss);
      ss = fmaf(spkL[c0 + 2], wv.z, ss); ss = fmaf(spkL[c0 + 3], wv.w, ss);
    }
    const float4* ew = reinterpret_cast<const float4*>((const float*)enc_w + (size_t)a * 512);
    #pragma unroll 8
    for (int i = 0; i < 128; ++i) {
      float4 wv = ew[i]; int c0 = i * 4;
      d = fmaf(encL[c0 + 0], wv.x, d); d = fmaf(encL[c0 + 1], wv.y, d);
      d = fmaf(encL[c0 + 2], wv.z, d); d = fmaf(encL[c0 + 3], wv.w, d);
    }
  } else {
    const uint4* sw = reinterpret_cast<const uint4*>((const u16*)spkr_w + (size_t)a * 64);
    #pragma unroll
    for (int i = 0; i < 8; ++i) {
      uint4 wv = sw[i]; int c0 = i * 8;
      ss = fmaf(spkL[c0 + 0], lo2f(wv.x), ss); ss = fmaf(spkL[c0 + 1], hi2f(wv.x), ss);
      ss = fmaf(spkL[c0 + 2], lo2f(wv.y), ss); ss = fmaf(spkL[c0 + 3], hi2f(wv.y), ss);
      ss = fmaf(spkL[c0 + 4], lo2f(wv.z), ss); ss = fmaf(spkL[c0 + 5], hi2f(wv.z), ss);
      ss = fmaf(spkL[c0 + 6], lo2f(wv.w), ss); ss = fmaf(spkL[c0 + 7], hi2f(wv.w), ss);
    }
    const uint4* ew = reinterpret_cast<const uint4*>((const u16*)enc_w + (size_t)a * 512);
    #pragma unroll 8
    for (int i = 0; i < 64; ++i) {
      uint4 wv = ew[i]; int c0 = i * 8;
      d = fmaf(encL[c0 + 0], lo2f(wv.x), d); d = fmaf(encL[c0 + 1], hi2f(wv.x), d);
      d = fmaf(encL[c0 + 2], lo2f(wv.y), d); d = fmaf(encL[c0 + 3], hi2f(wv.y), d);
      d = fmaf(encL[c0 + 4], lo2f(wv.z), d); d = fmaf(encL[c0 + 5], hi2f(wv.z), d);
      d = fmaf(encL[c0 + 6], lo2f(wv.w), d); d = fmaf(encL[c0 + 7], hi2f(wv.w), d);
    }
  }
  float bspk = ss / (1.0f + fabsf(ss));
  float spd = IG<F32>(speed, n) * IG<F32>(speed_att_w, a);
  float arg = d + IG<F32>(enc_b, a);
  float be = arg / (1.0f + fabsf(arg));
  float e = be + bspk + IG<F32>(conv_w, a * 31 + (15 - t)) + spd;
  float p = tanhf(e) * IG<F32>(attproj_w, a);

  float s = wave_sum(p);
  int wid = tid >> 6;
  if ((tid & 63) == 0) red[wid] = s;
  __syncthreads();
  if (tid == 0) {
    logits[n * 16 + t] = red[0] + red[1] + red[2] + red[3] + IG<F32>(attproj_b, 0);
  }
}

// ---------------------------------------------------------------------------
// k_ctx_e: per-n masked softmax over window + context
// ---------------------------------------------------------------------------
template<int F32>
__global__ __launch_bounds__(256) void k_ctx_e(
    const int* __restrict__ flag,
    const void* __restrict__ enc, const int* __restrict__ lengths,
    const float* __restrict__ logits, const float* __restrict__ sp,
    float* __restrict__ ctx, void* __restrict__ out)
{
  if (flag[0] != F32) return;
  int n = blockIdx.x, tid = threadIdx.x;
  __shared__ float wL[10];
  if (tid == 0) {
    int lm1 = lengths[n] - 1;
    float lf[10]; float m = -3.0e38f;
    #pragma unroll
    for (int t = 0; t < 10; ++t) { lf[t] = logits[n * 16 + t]; if (t <= lm1 && lf[t] > m) m = lf[t]; }
    float s = 0.0f, w[10];
    #pragma unroll
    for (int t = 0; t < 10; ++t) { w[t] = (t <= lm1) ? expf(lf[t] - m) : 0.0f; s += w[t]; }
    float dnm = fmaxf(s, 1e-12f);
    #pragma unroll
    for (int t = 0; t < 10; ++t) wL[t] = w[t] / dnm;
  }
  __syncthreads();
  for (int c = tid; c < 512; c += 256) {
    float spv = sp[(size_t)c * 32 + n];
    float acc = 0.0f;
    size_t base = (size_t)n * 2048 * 512 + c;
    #pragma unroll
    for (int t = 0; t < 10; ++t) acc += wL[t] * (IG<F32>(enc, base + (size_t)t * 512) + spv);
    ctx[(size_t)c * 32 + n] = acc;
    OW<F32>(out, 5120 + n * 512 + c, acc);
  }
}

// ---------------------------------------------------------------------------
// k_act_e: LSTM gate activation
// ---------------------------------------------------------------------------
__global__ __launch_bounds__(256) void k_act_e(const float* __restrict__ g, float* __restrict__ h)
{
  int f = blockIdx.x * 256 + threadIdx.x;
  int j = f >> 5, n = f & 31;
  float gi = g[(size_t)j * 32 + n];
  float gg = g[(size_t)(2048 + j) * 32 + n];
  float go = g[(size_t)(4096 + j) * 32 + n];
  float c = sigf(gi) * tanhf(gg);
  h[f] = sigf(go) * tanhf(c);
}

// ---------------------------------------------------------------------------
// k_ln_e: x = LayerNorm(x + delta) * g + b   (per n; 512 threads)
// ---------------------------------------------------------------------------
template<int F32>
__global__ __launch_bounds__(512) void k_ln_e(
    const int* __restrict__ flag,
    float* __restrict__ x, const float* __restrict__ delta,
    const void* __restrict__ lg, const void* __restrict__ lb)
{
  if (flag[0] != F32) return;
  int n = blockIdx.x, tid = threadIdx.x;
  __shared__ float red[18];
  float y = x[(size_t)tid * 32 + n] + delta[(size_t)tid * 32 + n];
  float s1 = wave_sum(y), s2 = wave_sum(y * y);
  int wid = tid >> 6;
  if ((tid & 63) == 0) { red[wid] = s1; red[8 + wid] = s2; }
  __syncthreads();
  if (tid == 0) {
    float t1 = 0, t2 = 0;
    for (int i = 0; i < 8; ++i) { t1 += red[i]; t2 += red[8 + i]; }
    float mu = t1 * (1.0f / 512.0f);
    float var = t2 * (1.0f / 512.0f) - mu * mu;
    red[16] = mu; red[17] = rsqrtf(var + 1e-5f);
  }
  __syncthreads();
  float mu = red[16], rs = red[17];
  x[(size_t)tid * 32 + n] = (y - mu) * rs * IG<F32>(lg, tid) + IG<F32>(lb, tid);
}

// ---------------------------------------------------------------------------
// k_out_e: final projection to (N,160)
// ---------------------------------------------------------------------------
template<int F32>
__global__ __launch_bounds__(256) void k_out_e(
    const int* __restrict__ flag,
    const float* __restrict__ x, const void* __restrict__ W, const void* __restrict__ bias,
    void* __restrict__ out)
{
  if (flag[0] != F32) return;
  int n = blockIdx.x, tid = threadIdx.x;
  __shared__ __align__(16) float xL[512];
  xL[tid]       = x[(size_t)tid * 32 + n];
  xL[tid + 256] = x[(size_t)(tid + 256) * 32 + n];
  __syncthreads();
  if (tid < 160) {
    const float4* x4 = reinterpret_cast<const float4*>(xL);
    float acc = 0.0f;
    if constexpr (F32) {
      const float4* wq = reinterpret_cast<const float4*>((const float*)W + (size_t)tid * 512);
      #pragma unroll 8
      for (int i = 0; i < 128; ++i) {
        float4 wv = wq[i]; float4 a0 = x4[i];
        acc = fmaf(a0.x, wv.x, acc); acc = fmaf(a0.y, wv.y, acc);
        acc = fmaf(a0.z, wv.z, acc); acc = fmaf(a0.w, wv.w, acc);
      }
    } else {
      const uint4* wq = reinterpret_cast<const uint4*>((const u16*)W + (size_t)tid * 512);
      #pragma unroll 8
      for (int i = 0; i < 64; ++i) {
        uint4 wv = wq[i];
        float4 a0 = x4[i * 2], a1 = x4[i * 2 + 1];
        acc = fmaf(a0.x, lo2f(wv.x), acc); acc = fmaf(a0.y, hi2f(wv.x), acc);
        acc = fmaf(a0.z, lo2f(wv.y), acc); acc = fmaf(a0.w, hi2f(wv.y), acc);
        acc = fmaf(a1.x, lo2f(wv.z), acc); acc = fmaf(a1.y, hi2f(wv.z), acc);
        acc = fmaf(a1.z, lo2f(wv.w), acc); acc = fmaf(a1.w, hi2f(wv.w), acc);
      }
    }
    OW<F32>(out, n * 160 + tid, acc + IG<F32>(bias, tid));
  }
}

// ---------------------------------------------------------------------------
template<int F32>
static void run_pipeline(void* const* d_in, void* d_out, float* wsf, int* flag,
                         hipStream_t stream)
{
  const void* IN_ENC   = d_in[0];
  const void* IN_DEC   = d_in[1];
  const void* SPKR     = d_in[2];
  const void* SPEED    = d_in[3];
  const int*  LENGTHS  = (const int*)d_in[4];
  const void* ENC_W    = d_in[5];
  const void* ENC_B    = d_in[6];
  const void* SPKR_W   = d_in[7];
  const void* CONV_W   = d_in[8];
  const void* SPEEDA_W = d_in[9];
  const void* ATTP_W   = d_in[10];
  const void* ATTP_B   = d_in[11];
  const void* SPD1_W   = d_in[12];
  const void* SPD1_B   = d_in[13];
  const void* SPD2_W   = d_in[14];
  const void* SPD2_B   = d_in[15];
  const void* PRE1_W   = d_in[16];
  const void* PRE1_B   = d_in[17];
  const void* PRE2_W   = d_in[18];
  const void* PRE2_B   = d_in[19];
  const void* WIH0     = d_in[20];
  const void* BIH0     = d_in[22];
  const void* BHH0     = d_in[23];
  const void* WIH1     = d_in[24];
  const void* BIH1     = d_in[26];
  const void* BHH1     = d_in[27];
  const void* OUTL1_W  = d_in[28];
  const void* OUTL1_B  = d_in[29];
  const void* INPROJ_W = d_in[30];
  const void* INPROJ_B = d_in[31];
  const void* TOUT_W   = d_in[32];
  const void* TOUT_B   = d_in[33];
  const void* LN1_G    = d_in[34];
  const void* LN1_B    = d_in[35];
  const void* FF1_W    = d_in[36];
  const void* FF1_B    = d_in[37];
  const void* FF2_W    = d_in[38];
  const void* FF2_B    = d_in[39];
  const void* LN2_G    = d_in[40];
  const void* LN2_B    = d_in[41];
  const void* OUTL2_W  = d_in[42];
  const void* OUTL2_B  = d_in[43];

  float* pin     = wsf + 0;        // [144][32]
  float* hspd    = wsf + 4608;     // [512][32]
  float* spkr_rn = wsf + 20992;    // [64][32]
  float* sp      = wsf + 23040;    // [512][32]
  float* logits  = wsf + 39424;    // [32][16]
  float* ctx     = wsf + 39936;    // [512][32]
  float* prehid  = wsf + 56320;    // [1024][32]
  float* pre     = wsf + 89088;    // [512][32]
  float* g0      = wsf + 105472;   // [6144][32]
  float* h1      = wsf + 302080;   // [2048][32]
  float* g1      = g0;             // g0 dead after h1
  float* h2      = wsf + 367616;   // [2048][32]
  float* xs      = wsf + 433152;   // [512][32]
  float* vbuf    = wsf + 105472;   // transformer scratch in dead g0/g1 region
  float* abuf    = wsf + 121856;
  float* hbuf    = wsf + 138240;
  float* fbuf    = wsf + 171008;

  k_init_e<F32><<<90, 256, 0, stream>>>(flag, IN_DEC, SPKR, SPEED, SPD1_W, SPD1_B,
                                        pin, hspd, spkr_rn);
  // sp = tanh(spd2_w @ hspd + b)   M=512 K=512  (RPB=2 -> 256 blocks)
  k_gv_e<F32><<<256, 256, 0, stream>>>(flag, hspd, 512, hspd, 0, hspd, 0, hspd,
                                       SPD2_W, SPD2_B, nullptr, sp, 512, 0, 2, 2);
  k_attlog_e<F32><<<dim3(10, 32), 256, 0, stream>>>(flag, IN_ENC, SPKR, SPEED,
                                       ENC_W, ENC_B, SPKR_W, CONV_W, SPEEDA_W,
                                       ATTP_W, ATTP_B, logits);
  k_ctx_e<F32><<<32, 256, 0, stream>>>(flag, IN_ENC, LENGTHS, logits, sp, ctx, d_out);
  // prehid = relu(pre1_w @ pin + b)   M=1024 K=144  (RPB=2 -> 512 blocks)
  k_gv_e<F32><<<512, 256, 0, stream>>>(flag, pin, 144, pin, 0, pin, 0, pin,
                                       PRE1_W, PRE1_B, nullptr, prehid, 144, 0, 1, 2);
  // pre = relu(pre2_w @ prehid + b)   M=512 K=1024  (RPB=2 -> 256 blocks)
  k_gv_e<F32><<<256, 256, 0, stream>>>(flag, prehid, 1024, prehid, 0, prehid, 0, prehid,
                                       PRE2_W, PRE2_B, nullptr, pre, 1024, 0, 1, 2);
  // g0: rows 6144 (i,gg,o), K=1088  (RPB=8 -> 768 blocks, unchanged)
  k_gv_e<F32><<<768, 256, 0, stream>>>(flag, pre, 512, ctx, 512, spkr_rn, 64, pre,
                                       WIH0, BIH0, BHH0, g0, 1088, 1, 0, 8);
  k_act_e<<<256, 256, 0, stream>>>(g0, h1);
  // g1: rows 6144, K=2048  (RPB=8 -> 768 blocks, unchanged)
  k_gv_e<F32><<<768, 256, 0, stream>>>(flag, h1, 2048, h1, 0, h1, 0, h1,
                                       WIH1, BIH1, BHH1, g1, 2048, 1, 0, 8);
  k_act_e<<<256, 256, 0, stream>>>(g1, h2);
  // xs = outl1_w @ [h2,pre,ctx,spkr] + b   M=512 K=3136  (RPB=2 -> 256 blocks)
  k_gv_e<F32><<<256, 256, 0, stream>>>(flag, h2, 2048, pre, 512, ctx, 512, spkr_rn,
                                       OUTL1_W, OUTL1_B, nullptr, xs, 3136, 0, 0, 2);

  for (int l = 0; l < 2; ++l) {
    const char* Wv = (const char*)INPROJ_W; const char* bv = (const char*)INPROJ_B;
    const char* Wo = (const char*)TOUT_W;   const char* bo = (const char*)TOUT_B;
    const char* W1 = (const char*)FF1_W;    const char* W2 = (const char*)FF2_W;
    int esz = F32 ? 4 : 2;
    // v = Wv @ xs + bv      M=512 K=512  (RPB=2 -> 256 blocks)
    k_gv_e<F32><<<256, 256, 0, stream>>>(flag, xs, 512, xs, 0, xs, 0, xs,
        Wv + ((size_t)l * 786432 + 524288) * esz,
        bv + ((size_t)l * 1536 + 1024) * esz, nullptr, vbuf, 512, 0, 0, 2);
    // a = Wo @ v + bo       M=512 K=512  (RPB=2 -> 256 blocks)
    k_gv_e<F32><<<256, 256, 0, stream>>>(flag, vbuf, 512, vbuf, 0, vbuf, 0, vbuf,
        Wo + ((size_t)l * 262144) * esz,
        bo + ((size_t)l * 512) * esz, nullptr, abuf, 512, 0, 0, 2);
    k_ln_e<F32><<<32, 512, 0, stream>>>(flag, xs, abuf,
        (const char*)LN1_G + (size_t)l * 512 * esz,
        (const char*)LN1_B + (size_t)l * 512 * esz);
    // h = relu(W1 @ xs + b1)  M=1024 K=512  (RPB=2 -> 512 blocks)
    k_gv_e<F32><<<512, 256, 0, stream>>>(flag, xs, 512, xs, 0, xs, 0, xs,
        W1 + ((size_t)l * 524288) * esz,
        (const char*)FF1_B + (size_t)l * 1024 * esz, nullptr, hbuf, 512, 0, 1, 2);
    // f = W2 @ h + b2       M=512 K=1024  (RPB=2 -> 256 blocks)
    k_gv_e<F32><<<256, 256, 0, stream>>>(flag, hbuf, 1024, hbuf, 0, hbuf, 0, hbuf,
        W2 + ((size_t)l * 524288) * esz,
        (const char*)FF2_B + (size_t)l * 512 * esz, nullptr, fbuf, 1024, 0, 0, 2);
    k_ln_e<F32><<<32, 512, 0, stream>>>(flag, xs, fbuf,
        (const char*)LN2_G + (size_t)l * 512 * esz,
        (const char*)LN2_B + (size_t)l * 512 * esz);
  }

  k_out_e<F32><<<32, 256, 0, stream>>>(flag, xs, OUTL2_W, OUTL2_B, d_out);
}

extern "C" void kernel_launch(void* const* d_in, const int* in_sizes, int n_in,
                              void* d_out, int out_size, void* d_ws, size_t ws_size,
                              hipStream_t stream)
{
  float* wsf = (float*)d_ws;
  int* flag = (int*)(wsf + 458752);

  k_detect_e<<<1, 64, 0, stream>>>(d_in[3], flag);

  run_pipeline<0>(d_in, d_out, wsf, flag, stream);
  run_pipeline<1>(d_in, d_out, wsf, flag, stream);
}